// Round 1
// baseline (2938.441 us; speedup 1.0000x reference)
//
#include <hip/hip_runtime.h>
#include <hip/hip_bf16.h>

#define EPSV 1e-5f

__device__ __forceinline__ int deg_of(int m) {
  return (m == 0) ? 0 : (m < 4 ? 1 : (m < 9 ? 2 : (m < 16 ? 3 : 4)));
}
__device__ __forceinline__ float silu_f(float v) { return v / (1.f + __expf(-v)); }
// round-to-nearest-even f32 -> bf16 bits (values are finite, moderate range)
__device__ __forceinline__ unsigned short f2bf(float v) {
  unsigned int u = __float_as_uint(v);
  unsigned int r = (u + 0x7FFFu + ((u >> 16) & 1u)) >> 16;
  return (unsigned short)r;
}
__device__ __forceinline__ float bf2f(unsigned int ubits16) {
  return __uint_as_float(ubits16 << 16);
}

// LDS layout (float indices):
//  XB  = 0      : x / xn            [25][68]   (1700)
//  HB  = 1700   : h1, later hb      [25][68]   (1700)
//  TG  = 3400   : to_grid^T [m][s]  [25][68]   (1700)
//  GB  = 5100   : g [64][65] f32 ; later t2 bf16 [64][130]   (4160 f)
//  T1  = 9260   : t1 bf16 [64][130]; later g3 f32 [64][65]   (4160 f)
//  GA  = 13420  : gating [64]
//  RD  = 13484  : reduce  [256]
// total 13740 floats = 54,960 B  -> 2 blocks/CU

__global__ __launch_bounds__(256, 2) void fused_sample_kernel(
    const float* __restrict__ x,
    const float* __restrict__ nl0w, const float* __restrict__ nl0b,
    const float* __restrict__ affw,
    const float* __restrict__ l1w,  const float* __restrict__ l1b,
    const float* __restrict__ scw,  const float* __restrict__ scb,
    const float* __restrict__ gw1,  const float* __restrict__ gw2,
    const float* __restrict__ gw3,
    const float* __restrict__ l2w,  const float* __restrict__ l2b,
    const float* __restrict__ tgm,
    float* __restrict__ out, int nTot)
{
  __shared__ float sm[13740];
  float* XB = sm;
  float* HB = sm + 1700;
  float* TG = sm + 3400;
  float* GB = sm + 5100;
  float* T1 = sm + 9260;
  float* GA = sm + 13420;
  float* RD = sm + 13484;

  const int t = threadIdx.x;
  const int n = blockIdx.x;
  if (n >= nTot) return;

  const float* gx = x + (size_t)n * 1600;

  // ---- phase 0: stage x and to_grid^T into LDS ----
  for (int f = 4 * t; f < 1600; f += 1024) {
    float4 v = *(const float4*)(gx + f);
    int m = f >> 6, c = f & 63;
    *(float4*)(XB + m * 68 + c) = v;
  }
  for (int f = t; f < 1600; f += 256) {
    int s = f / 25;
    int m = f - s * 25;
    TG[m * 68 + s] = tgm[f];
  }
  __syncthreads();

  // ---- phase 1: norms ----
  {
    float part = 0.f;
    for (int f = 64 + t; f < 1600; f += 256) {
      int m = f >> 6, c = f & 63;
      float v = XB[m * 68 + c];
      int l = deg_of(m);
      float bw = 1.f / (float)((2 * l + 1) * 4);
      part += v * v * bw;
    }
    RD[t] = part;
  }
  __syncthreads();
  if (t < 64) {
    // wave 0: reduce fnorm total -> inv
    float s4 = RD[t] + RD[t + 64] + RD[t + 128] + RD[t + 192];
    #pragma unroll
    for (int o = 32; o >= 1; o >>= 1) s4 += __shfl_xor(s4, o, 64);
    if (t == 0) RD[0] = rsqrtf(s4 * (1.f / 64.f) + EPSV);
  } else if (t < 128) {
    // wave 1: layernorm of row 0 (in place)
    int c = t - 64;
    float v = XB[c];
    float s1 = v, s2 = v * v;
    #pragma unroll
    for (int o = 32; o >= 1; o >>= 1) {
      s1 += __shfl_xor(s1, o, 64);
      s2 += __shfl_xor(s2, o, 64);
    }
    float mu  = s1 * (1.f / 64.f);
    float var = s2 * (1.f / 64.f) - mu * mu;
    XB[c] = (v - mu) * rsqrtf(var + EPSV) * nl0w[c] + nl0b[c];
  }
  __syncthreads();
  {
    float inv = RD[0];
    for (int f = 64 + t; f < 1600; f += 256) {
      int m = f >> 6, c = f & 63;
      int l = deg_of(m);
      XB[m * 68 + c] *= inv * affw[(l - 1) * 64 + c];
    }
  }
  __syncthreads();

  // ---- phase 2: gating (wave 0 lanes) ----
  if (t < 64) {
    float acc = scb[t];
    #pragma unroll 8
    for (int c0 = 0; c0 < 64; ++c0) acc += XB[c0] * scw[c0 * 64 + t];
    GA[t] = silu_f(acc);
  }

  // ---- phase 3: h1 = xn @ lin1_w[deg]  (wave-partitioned by degree group) ----
  {
    const int w = t >> 6, o = t & 63;
    int m0 = (w == 0) ? 0 : (w == 1) ? 4 : (w == 2) ? 9 : 16;
    int m1 = (w == 0) ? 4 : (w == 1) ? 9 : (w == 2) ? 16 : 25;
    float acc[9];
    #pragma unroll
    for (int j = 0; j < 9; ++j) acc[j] = 0.f;
    const float* wA = l1w + deg_of(m0) * 4096 + o;
    const float* wB = l1w + 4096 + o;  // l=1 stream (wave 0 rows 1..3)
    #pragma unroll 4
    for (int i = 0; i < 64; ++i) {
      float a = wA[i * 64];
      float b = (w == 0) ? wB[i * 64] : a;
      #pragma unroll
      for (int j = 0; j < 9; ++j) {
        int mm = m0 + j; if (mm > 24) mm = 24;
        float coef = (w == 0 && j > 0) ? b : a;
        acc[j] += XB[mm * 68 + i] * coef;
      }
    }
    for (int j = 0; j < m1 - m0; ++j) {
      float v = acc[j] + ((m0 + j) == 0 ? l1b[o] : 0.f);
      HB[(m0 + j) * 68 + o] = v;
    }
  }
  __syncthreads();

  // ---- phase 3b: g[s][h] = sum_m to_grid[s][m] * h1[m][h] ----
  {
    const int h = t & 63, sb = t >> 6;  // wave handles s in [sb*16, sb*16+16)
    float acc[16];
    #pragma unroll
    for (int k = 0; k < 16; ++k) acc[k] = 0.f;
    #pragma unroll 5
    for (int m = 0; m < 25; ++m) {
      float hv = HB[m * 68 + h];
      #pragma unroll
      for (int q = 0; q < 4; ++q) {
        float4 tg4 = *(const float4*)(TG + m * 68 + sb * 16 + 4 * q);
        acc[4 * q + 0] += tg4.x * hv;
        acc[4 * q + 1] += tg4.y * hv;
        acc[4 * q + 2] += tg4.z * hv;
        acc[4 * q + 3] += tg4.w * hv;
      }
    }
    #pragma unroll
    for (int k = 0; k < 16; ++k) GB[(sb * 16 + k) * 65 + h] = acc[k];
  }
  __syncthreads();

  unsigned short* T1u = reinterpret_cast<unsigned short*>(T1);
  unsigned short* T2u = reinterpret_cast<unsigned short*>(GB);

  // ---- phase 4: t1 = silu(g @ w1)  [64x64 @ 64x128] ----
  {
    const int s  = t & 63;
    const int jb = __builtin_amdgcn_readfirstlane((t >> 6) * 32);
    float acc[32];
    #pragma unroll
    for (int j = 0; j < 32; ++j) acc[j] = 0.f;
    #pragma unroll 2
    for (int k = 0; k < 64; ++k) {
      float gv = GB[s * 65 + k];
      const float4* wp = (const float4*)(gw1 + k * 128 + jb);
      #pragma unroll
      for (int q = 0; q < 8; ++q) {
        float4 wv = wp[q];
        acc[4 * q + 0] += gv * wv.x;
        acc[4 * q + 1] += gv * wv.y;
        acc[4 * q + 2] += gv * wv.z;
        acc[4 * q + 3] += gv * wv.w;
      }
    }
    #pragma unroll
    for (int j = 0; j < 32; j += 2) {
      unsigned int lo = f2bf(silu_f(acc[j]));
      unsigned int hi = f2bf(silu_f(acc[j + 1]));
      *(unsigned int*)(T1u + s * 130 + jb + j) = lo | (hi << 16);
    }
  }
  __syncthreads();

  // ---- phase 5: t2 = silu(t1 @ w2)  [64x128 @ 128x128], t2 overlays g ----
  {
    const int s  = t & 63;
    const int jb = __builtin_amdgcn_readfirstlane((t >> 6) * 32);
    float acc[32];
    #pragma unroll
    for (int j = 0; j < 32; ++j) acc[j] = 0.f;
    #pragma unroll 2
    for (int k = 0; k < 128; k += 2) {
      unsigned int u = *(const unsigned int*)(T1u + s * 130 + k);
      float tlo = __uint_as_float(u << 16);
      float thi = __uint_as_float(u & 0xFFFF0000u);
      const float4* wp0 = (const float4*)(gw2 + k * 128 + jb);
      const float4* wp1 = (const float4*)(gw2 + (k + 1) * 128 + jb);
      #pragma unroll
      for (int q = 0; q < 8; ++q) {
        float4 w0 = wp0[q];
        acc[4 * q + 0] += tlo * w0.x; acc[4 * q + 1] += tlo * w0.y;
        acc[4 * q + 2] += tlo * w0.z; acc[4 * q + 3] += tlo * w0.w;
      }
      #pragma unroll
      for (int q = 0; q < 8; ++q) {
        float4 w1v = wp1[q];
        acc[4 * q + 0] += thi * w1v.x; acc[4 * q + 1] += thi * w1v.y;
        acc[4 * q + 2] += thi * w1v.z; acc[4 * q + 3] += thi * w1v.w;
      }
    }
    #pragma unroll
    for (int j = 0; j < 32; j += 2) {
      unsigned int lo = f2bf(silu_f(acc[j]));
      unsigned int hi = f2bf(silu_f(acc[j + 1]));
      *(unsigned int*)(T2u + s * 130 + jb + j) = lo | (hi << 16);
    }
  }
  __syncthreads();

  // ---- phase 6: g3 = t2 @ w3  [64x128 @ 128x64], g3 overlays t1 (f32, stride 65) ----
  float* G3 = T1;
  {
    const int s  = t & 63;
    const int jb = __builtin_amdgcn_readfirstlane((t >> 6) * 16);
    float acc[16];
    #pragma unroll
    for (int j = 0; j < 16; ++j) acc[j] = 0.f;
    #pragma unroll 2
    for (int k = 0; k < 128; k += 2) {
      unsigned int u = *(const unsigned int*)(T2u + s * 130 + k);
      float tlo = __uint_as_float(u << 16);
      float thi = __uint_as_float(u & 0xFFFF0000u);
      const float4* wp0 = (const float4*)(gw3 + k * 64 + jb);
      const float4* wp1 = (const float4*)(gw3 + (k + 1) * 64 + jb);
      #pragma unroll
      for (int q = 0; q < 4; ++q) {
        float4 w0 = wp0[q];
        acc[4 * q + 0] += tlo * w0.x; acc[4 * q + 1] += tlo * w0.y;
        acc[4 * q + 2] += tlo * w0.z; acc[4 * q + 3] += tlo * w0.w;
      }
      #pragma unroll
      for (int q = 0; q < 4; ++q) {
        float4 w1v = wp1[q];
        acc[4 * q + 0] += thi * w1v.x; acc[4 * q + 1] += thi * w1v.y;
        acc[4 * q + 2] += thi * w1v.z; acc[4 * q + 3] += thi * w1v.w;
      }
    }
    #pragma unroll
    for (int j = 0; j < 16; ++j) G3[s * 65 + jb + j] = acc[j];
  }
  __syncthreads();

  // ---- phase 7: hb[m][h] = sum_s TG[m][s] * g3[s][h]  (m=1..24); hb[0]=gating ----
  {
    const int h = t & 63, w = t >> 6;
    const int mb = 1 + w * 6;
    float acc[6];
    #pragma unroll
    for (int j = 0; j < 6; ++j) acc[j] = 0.f;
    #pragma unroll 4
    for (int s = 0; s < 64; ++s) {
      float gv = G3[s * 65 + h];
      #pragma unroll
      for (int j = 0; j < 6; ++j) acc[j] += TG[(mb + j) * 68 + s] * gv;
    }
    #pragma unroll
    for (int j = 0; j < 6; ++j) HB[(mb + j) * 68 + h] = acc[j];
    if (t < 64) HB[t] = GA[t];
  }
  __syncthreads();

  // ---- phase 8: out = hb @ lin2_w[deg] (+ lin2_b on row 0) ----
  {
    const int w = t >> 6, o = t & 63;
    int m0 = (w == 0) ? 0 : (w == 1) ? 4 : (w == 2) ? 9 : 16;
    int m1 = (w == 0) ? 4 : (w == 1) ? 9 : (w == 2) ? 16 : 25;
    float acc[9];
    #pragma unroll
    for (int j = 0; j < 9; ++j) acc[j] = 0.f;
    const float* wA = l2w + deg_of(m0) * 4096 + o;
    const float* wB = l2w + 4096 + o;
    #pragma unroll 4
    for (int i = 0; i < 64; ++i) {
      float a = wA[i * 64];
      float b = (w == 0) ? wB[i * 64] : a;
      #pragma unroll
      for (int j = 0; j < 9; ++j) {
        int mm = m0 + j; if (mm > 24) mm = 24;
        float coef = (w == 0 && j > 0) ? b : a;
        acc[j] += HB[mm * 68 + i] * coef;
      }
    }
    float* go = out + (size_t)n * 1600;
    for (int j = 0; j < m1 - m0; ++j) {
      float v = acc[j] + ((m0 + j) == 0 ? l2b[o] : 0.f);
      go[(m0 + j) * 64 + o] = v;
    }
  }
}

extern "C" void kernel_launch(void* const* d_in, const int* in_sizes, int n_in,
                              void* d_out, int out_size, void* d_ws, size_t ws_size,
                              hipStream_t stream) {
  const float* x    = (const float*)d_in[0];
  const float* nl0w = (const float*)d_in[1];
  const float* nl0b = (const float*)d_in[2];
  const float* affw = (const float*)d_in[3];
  const float* l1w  = (const float*)d_in[4];
  const float* l1b  = (const float*)d_in[5];
  const float* scw  = (const float*)d_in[6];
  const float* scb  = (const float*)d_in[7];
  const float* gw1  = (const float*)d_in[8];
  const float* gw2  = (const float*)d_in[9];
  const float* gw3  = (const float*)d_in[10];
  const float* l2w  = (const float*)d_in[11];
  const float* l2b  = (const float*)d_in[12];
  const float* tgm  = (const float*)d_in[13];

  int N = in_sizes[0] / 1600;
  fused_sample_kernel<<<dim3(N), dim3(256), 0, stream>>>(
      x, nl0w, nl0b, affw, l1w, l1b, scw, scb,
      gw1, gw2, gw3, l2w, l2b, tgm, (float*)d_out, N);
}

// Round 2
// 1230.301 us; speedup vs baseline: 2.3884x; 2.3884x over previous
//
#include <hip/hip_runtime.h>
#include <hip/hip_bf16.h>

#define EPSV 1e-5f

typedef __attribute__((ext_vector_type(8))) short short8;
typedef __attribute__((ext_vector_type(4))) float f32x4;

__device__ __forceinline__ int deg_of(int m) {
  return (m == 0) ? 0 : (m < 4 ? 1 : (m < 9 ? 2 : (m < 16 ? 3 : 4)));
}
__device__ __forceinline__ float silu_f(float v) { return v / (1.f + __expf(-v)); }
// round-to-nearest-even f32 -> bf16 bits
__device__ __forceinline__ unsigned short f2bf(float v) {
  unsigned int u = __float_as_uint(v);
  unsigned int r = (u + 0x7FFFu + ((u >> 16) & 1u)) >> 16;
  return (unsigned short)r;
}

// LDS layout (float indices), 12076 floats = 48304 B -> 3 blocks/CU:
//  XB  = 0     : x / xn          [25][68] f32   (1700)   dead after phase 3
//  HB  = 1700  : h1, later hb    [25][68] f32   (1700)   h1 dead after 3b
//  GBF = 3400  : g bf16 [64][72]                (2304 f) dead after phase 4
//  TG  = 5704  : to_grid^T [m][s][25][68] f32   (1700)   live to phase 7
//  T1  = 7404  : t1 bf16 [64][136] (4352 f); later G3 f32 [64][65] (4160)
//  GA  = 11756 : gating [64]
//  RD  = 11820 : reduce  [256]
//  T2  overlays floats 0..4352 as bf16 [64][136] (XB/HB/gbf all dead by phase 5)

__global__ __launch_bounds__(256, 3) void fused_sample_kernel(
    const float* __restrict__ x,
    const float* __restrict__ nl0w, const float* __restrict__ nl0b,
    const float* __restrict__ affw,
    const float* __restrict__ l1w,  const float* __restrict__ l1b,
    const float* __restrict__ scw,  const float* __restrict__ scb,
    const float* __restrict__ gw1,  const float* __restrict__ gw2,
    const float* __restrict__ gw3,
    const float* __restrict__ l2w,  const float* __restrict__ l2b,
    const float* __restrict__ tgm,
    float* __restrict__ out, int nTot)
{
  __shared__ float sm[12076];
  float* XB = sm;
  float* HB = sm + 1700;
  unsigned short* GBu = (unsigned short*)(sm + 3400);  // g bf16, stride 72
  float* TG = sm + 5704;
  unsigned short* T1u = (unsigned short*)(sm + 7404);  // t1 bf16, stride 136
  float* G3 = sm + 7404;                                // g3 f32, stride 65
  float* GA = sm + 11756;
  float* RD = sm + 11820;
  unsigned short* T2u = (unsigned short*)sm;            // t2 bf16, stride 136

  const int t = threadIdx.x;
  const int n = blockIdx.x;
  if (n >= nTot) return;

  const int W    = t >> 6;
  const int lane = t & 63;
  const int quad = lane >> 4;
  const int l16  = lane & 15;

  const float* gx = x + (size_t)n * 1600;

  // ---- phase 0: stage x and to_grid^T into LDS ----
  for (int f = 4 * t; f < 1600; f += 1024) {
    float4 v = *(const float4*)(gx + f);
    int m = f >> 6, c = f & 63;
    *(float4*)(XB + m * 68 + c) = v;
  }
  for (int f = t; f < 1600; f += 256) {
    int s = f / 25;
    int m = f - s * 25;
    TG[m * 68 + s] = tgm[f];
  }
  __syncthreads();

  // ---- phase 1: norms ----
  {
    float part = 0.f;
    for (int f = 64 + t; f < 1600; f += 256) {
      int m = f >> 6, c = f & 63;
      float v = XB[m * 68 + c];
      int l = deg_of(m);
      float bw = 1.f / (float)((2 * l + 1) * 4);
      part += v * v * bw;
    }
    RD[t] = part;
  }
  __syncthreads();
  if (t < 64) {
    float s4 = RD[t] + RD[t + 64] + RD[t + 128] + RD[t + 192];
    #pragma unroll
    for (int o = 32; o >= 1; o >>= 1) s4 += __shfl_xor(s4, o, 64);
    if (t == 0) RD[0] = rsqrtf(s4 * (1.f / 64.f) + EPSV);
  } else if (t < 128) {
    int c = t - 64;
    float v = XB[c];
    float s1 = v, s2 = v * v;
    #pragma unroll
    for (int o = 32; o >= 1; o >>= 1) {
      s1 += __shfl_xor(s1, o, 64);
      s2 += __shfl_xor(s2, o, 64);
    }
    float mu  = s1 * (1.f / 64.f);
    float var = s2 * (1.f / 64.f) - mu * mu;
    XB[c] = (v - mu) * rsqrtf(var + EPSV) * nl0w[c] + nl0b[c];
  }
  __syncthreads();
  {
    float inv = RD[0];
    for (int f = 64 + t; f < 1600; f += 256) {
      int m = f >> 6, c = f & 63;
      int l = deg_of(m);
      XB[m * 68 + c] *= inv * affw[(l - 1) * 64 + c];
    }
  }
  __syncthreads();

  // ---- phase 2: gating (wave 0) ----
  if (t < 64) {
    float acc = scb[t];
    #pragma unroll 8
    for (int c0 = 0; c0 < 64; ++c0) acc += XB[c0] * scw[c0 * 64 + t];
    GA[t] = silu_f(acc);
  }

  // ---- phase 3: h1 = xn @ lin1_w[deg] (wave-partitioned by degree group) ----
  {
    const int w = W, o = lane;
    int m0 = (w == 0) ? 0 : (w == 1) ? 4 : (w == 2) ? 9 : 16;
    int m1 = (w == 0) ? 4 : (w == 1) ? 9 : (w == 2) ? 16 : 25;
    float acc[9];
    #pragma unroll
    for (int j = 0; j < 9; ++j) acc[j] = 0.f;
    const float* wA = l1w + deg_of(m0) * 4096 + o;
    const float* wB = l1w + 4096 + o;
    #pragma unroll 4
    for (int i = 0; i < 64; ++i) {
      float a = wA[i * 64];
      float b = (w == 0) ? wB[i * 64] : a;
      #pragma unroll
      for (int j = 0; j < 9; ++j) {
        int mm = m0 + j; if (mm > 24) mm = 24;
        float coef = (w == 0 && j > 0) ? b : a;
        acc[j] += XB[mm * 68 + i] * coef;
      }
    }
    for (int j = 0; j < m1 - m0; ++j) {
      float v = acc[j] + ((m0 + j) == 0 ? l1b[o] : 0.f);
      HB[(m0 + j) * 68 + o] = v;
    }
  }
  __syncthreads();

  // ---- phase 3b: g[s][h] = sum_m to_grid[s][m] * h1[m][h], store bf16 ----
  {
    const int h = lane, sb = W;
    float acc[16];
    #pragma unroll
    for (int k = 0; k < 16; ++k) acc[k] = 0.f;
    #pragma unroll 5
    for (int m = 0; m < 25; ++m) {
      float hv = HB[m * 68 + h];
      #pragma unroll
      for (int q = 0; q < 4; ++q) {
        float4 tg4 = *(const float4*)(TG + m * 68 + sb * 16 + 4 * q);
        acc[4 * q + 0] += tg4.x * hv;
        acc[4 * q + 1] += tg4.y * hv;
        acc[4 * q + 2] += tg4.z * hv;
        acc[4 * q + 3] += tg4.w * hv;
      }
    }
    #pragma unroll
    for (int k = 0; k < 16; ++k) GBu[(sb * 16 + k) * 72 + h] = f2bf(acc[k]);
  }
  __syncthreads();

  // ---- phase 4 (MFMA): t1 = silu(g @ w1), 64x64 @ 64x128 ----
  {
    // B-frags: nt2 in {0,1} (cols (2W+nt2)*16..+16), ks in {0,1}
    short8 bf[4];
    #pragma unroll
    for (int nt2 = 0; nt2 < 2; ++nt2)
      #pragma unroll
      for (int ks = 0; ks < 2; ++ks) {
        const float* wp = gw1 + (size_t)(ks * 32 + quad * 8) * 128 + (2 * W + nt2) * 16 + l16;
        short8 bb;
        #pragma unroll
        for (int j = 0; j < 8; ++j) bb[j] = (short)f2bf(wp[j * 128]);
        bf[nt2 * 2 + ks] = bb;
      }
    f32x4 acc[8];
    #pragma unroll
    for (int i = 0; i < 8; ++i) acc[i] = (f32x4){0.f, 0.f, 0.f, 0.f};
    #pragma unroll
    for (int mt = 0; mt < 4; ++mt)
      #pragma unroll
      for (int ks = 0; ks < 2; ++ks) {
        short8 a = *(const short8*)(GBu + (mt * 16 + l16) * 72 + ks * 32 + quad * 8);
        acc[mt * 2 + 0] = __builtin_amdgcn_mfma_f32_16x16x32_bf16(a, bf[ks],     acc[mt * 2 + 0], 0, 0, 0);
        acc[mt * 2 + 1] = __builtin_amdgcn_mfma_f32_16x16x32_bf16(a, bf[2 + ks], acc[mt * 2 + 1], 0, 0, 0);
      }
    __syncthreads();  // everyone done reading GBu (and XB/HB safe for t2 later)
    #pragma unroll
    for (int mt = 0; mt < 4; ++mt)
      #pragma unroll
      for (int nt2 = 0; nt2 < 2; ++nt2) {
        int col = (2 * W + nt2) * 16 + l16;
        #pragma unroll
        for (int r = 0; r < 4; ++r) {
          int srow = mt * 16 + quad * 4 + r;
          T1u[srow * 136 + col] = f2bf(silu_f(acc[mt * 2 + nt2][r]));
        }
      }
  }
  __syncthreads();

  // ---- phase 5 (MFMA): t2 = silu(t1 @ w2), 64x128 @ 128x128 ----
  {
    short8 bf[8];
    #pragma unroll
    for (int nt2 = 0; nt2 < 2; ++nt2)
      #pragma unroll
      for (int ks = 0; ks < 4; ++ks) {
        const float* wp = gw2 + (size_t)(ks * 32 + quad * 8) * 128 + (2 * W + nt2) * 16 + l16;
        short8 bb;
        #pragma unroll
        for (int j = 0; j < 8; ++j) bb[j] = (short)f2bf(wp[j * 128]);
        bf[nt2 * 4 + ks] = bb;
      }
    f32x4 acc[8];
    #pragma unroll
    for (int i = 0; i < 8; ++i) acc[i] = (f32x4){0.f, 0.f, 0.f, 0.f};
    #pragma unroll
    for (int mt = 0; mt < 4; ++mt)
      #pragma unroll
      for (int ks = 0; ks < 4; ++ks) {
        short8 a = *(const short8*)(T1u + (mt * 16 + l16) * 136 + ks * 32 + quad * 8);
        acc[mt * 2 + 0] = __builtin_amdgcn_mfma_f32_16x16x32_bf16(a, bf[ks],     acc[mt * 2 + 0], 0, 0, 0);
        acc[mt * 2 + 1] = __builtin_amdgcn_mfma_f32_16x16x32_bf16(a, bf[4 + ks], acc[mt * 2 + 1], 0, 0, 0);
      }
    __syncthreads();  // done reading t1; t2 overlays XB/HB/GBF region
    #pragma unroll
    for (int mt = 0; mt < 4; ++mt)
      #pragma unroll
      for (int nt2 = 0; nt2 < 2; ++nt2) {
        int col = (2 * W + nt2) * 16 + l16;
        #pragma unroll
        for (int r = 0; r < 4; ++r) {
          int srow = mt * 16 + quad * 4 + r;
          T2u[srow * 136 + col] = f2bf(silu_f(acc[mt * 2 + nt2][r]));
        }
      }
  }
  __syncthreads();

  // ---- phase 6 (MFMA): g3 = t2 @ w3, 64x128 @ 128x64; G3 f32 overlays t1 ----
  {
    short8 bf[4];
    #pragma unroll
    for (int ks = 0; ks < 4; ++ks) {
      const float* wp = gw3 + (size_t)(ks * 32 + quad * 8) * 64 + W * 16 + l16;
      short8 bb;
      #pragma unroll
      for (int j = 0; j < 8; ++j) bb[j] = (short)f2bf(wp[j * 64]);
      bf[ks] = bb;
    }
    f32x4 acc[4];
    #pragma unroll
    for (int i = 0; i < 4; ++i) acc[i] = (f32x4){0.f, 0.f, 0.f, 0.f};
    #pragma unroll
    for (int mt = 0; mt < 4; ++mt)
      #pragma unroll
      for (int ks = 0; ks < 4; ++ks) {
        short8 a = *(const short8*)(T2u + (mt * 16 + l16) * 136 + ks * 32 + quad * 8);
        acc[mt] = __builtin_amdgcn_mfma_f32_16x16x32_bf16(a, bf[ks], acc[mt], 0, 0, 0);
      }
    __syncthreads();  // done reading t2 and t1 region before G3 overlays t1
    #pragma unroll
    for (int mt = 0; mt < 4; ++mt) {
      int col = W * 16 + l16;
      #pragma unroll
      for (int r = 0; r < 4; ++r) {
        int srow = mt * 16 + quad * 4 + r;
        G3[srow * 65 + col] = acc[mt][r];
      }
    }
  }
  __syncthreads();

  // ---- phase 7: hb[m][h] = sum_s TG[m][s] * g3[s][h] (m=1..24); hb[0]=gating ----
  {
    const int h = lane;
    const int mb = 1 + W * 6;
    float acc[6];
    #pragma unroll
    for (int j = 0; j < 6; ++j) acc[j] = 0.f;
    #pragma unroll 4
    for (int s = 0; s < 64; ++s) {
      float gv = G3[s * 65 + h];
      #pragma unroll
      for (int j = 0; j < 6; ++j) acc[j] += TG[(mb + j) * 68 + s] * gv;
    }
    #pragma unroll
    for (int j = 0; j < 6; ++j) HB[(mb + j) * 68 + h] = acc[j];
    if (t < 64) HB[t] = GA[t];
  }
  __syncthreads();

  // ---- phase 8: out = hb @ lin2_w[deg] (+ lin2_b on row 0) ----
  {
    const int w = W, o = lane;
    int m0 = (w == 0) ? 0 : (w == 1) ? 4 : (w == 2) ? 9 : 16;
    int m1 = (w == 0) ? 4 : (w == 1) ? 9 : (w == 2) ? 16 : 25;
    float acc[9];
    #pragma unroll
    for (int j = 0; j < 9; ++j) acc[j] = 0.f;
    const float* wA = l2w + deg_of(m0) * 4096 + o;
    const float* wB = l2w + 4096 + o;
    #pragma unroll 4
    for (int i = 0; i < 64; ++i) {
      float a = wA[i * 64];
      float b = (w == 0) ? wB[i * 64] : a;
      #pragma unroll
      for (int j = 0; j < 9; ++j) {
        int mm = m0 + j; if (mm > 24) mm = 24;
        float coef = (w == 0 && j > 0) ? b : a;
        acc[j] += HB[mm * 68 + i] * coef;
      }
    }
    float* go = out + (size_t)n * 1600;
    for (int j = 0; j < m1 - m0; ++j) {
      float v = acc[j] + ((m0 + j) == 0 ? l2b[o] : 0.f);
      go[(m0 + j) * 64 + o] = v;
    }
  }
}

extern "C" void kernel_launch(void* const* d_in, const int* in_sizes, int n_in,
                              void* d_out, int out_size, void* d_ws, size_t ws_size,
                              hipStream_t stream) {
  const float* x    = (const float*)d_in[0];
  const float* nl0w = (const float*)d_in[1];
  const float* nl0b = (const float*)d_in[2];
  const float* affw = (const float*)d_in[3];
  const float* l1w  = (const float*)d_in[4];
  const float* l1b  = (const float*)d_in[5];
  const float* scw  = (const float*)d_in[6];
  const float* scb  = (const float*)d_in[7];
  const float* gw1  = (const float*)d_in[8];
  const float* gw2  = (const float*)d_in[9];
  const float* gw3  = (const float*)d_in[10];
  const float* l2w  = (const float*)d_in[11];
  const float* l2b  = (const float*)d_in[12];
  const float* tgm  = (const float*)d_in[13];

  int N = in_sizes[0] / 1600;
  fused_sample_kernel<<<dim3(N), dim3(256), 0, stream>>>(
      x, nl0w, nl0b, affw, l1w, l1b, scw, scb,
      gw1, gw2, gw3, l2w, l2b, tgm, (float*)d_out, N);
}

// Round 3
// 798.547 us; speedup vs baseline: 3.6797x; 1.5407x over previous
//
#include <hip/hip_runtime.h>
#include <hip/hip_bf16.h>

#define EPSV 1e-5f

typedef __attribute__((ext_vector_type(8))) short short8;
typedef __attribute__((ext_vector_type(4))) float f32x4;

__device__ __forceinline__ int deg_of(int m) {
  return (m == 0) ? 0 : (m < 4 ? 1 : (m < 9 ? 2 : (m < 16 ? 3 : 4)));
}
__device__ __forceinline__ float silu_f(float v) { return v / (1.f + __expf(-v)); }
// round-to-nearest-even f32 -> bf16 bits
__device__ __forceinline__ unsigned short f2bf(float v) {
  unsigned int u = __float_as_uint(v);
  return (unsigned short)((u + 0x7FFFu + ((u >> 16) & 1u)) >> 16);
}
__device__ __forceinline__ short bfs(float v) { return (short)f2bf(v); }

// LDS layout (float indices), 9856 floats = 39,424 B -> 4 blocks/CU.
// Region A [0,4352):   XB f32 [25][68] (ph0-1b) -> T1u bf16 [64][136] (ph4-5)
//                      -> G3u bf16 [64][72] (ph6-7)
// Region B [4352,8704): XBh bf16 [32][72] @4352 (1b-3), H1u bf16 [64][40] @5504 (3-3b),
//                       GBu bf16 [64][72] @6784 (3b-4)  -> T2u bf16 [64][136] @4352 (5-6)
// Region C [8704,9856): RD f32 [256] (ph1) -> HBh bf16 [32][72] (ph7-8)

__global__ __launch_bounds__(256, 4) void fused_sample_kernel(
    const float* __restrict__ x,
    const float* __restrict__ nl0w, const float* __restrict__ nl0b,
    const float* __restrict__ affw,
    const float* __restrict__ l1w,  const float* __restrict__ l1b,
    const float* __restrict__ scw,  const float* __restrict__ scb,
    const float* __restrict__ gw1,  const float* __restrict__ gw2,
    const float* __restrict__ gw3,
    const float* __restrict__ l2w,  const float* __restrict__ l2b,
    const float* __restrict__ tgm,
    float* __restrict__ out, int nTot)
{
  __shared__ float sm[9856];
  float*          XB  = sm;                                   // [25][68] f32
  unsigned short* T1u = (unsigned short*)sm;                  // [64][136]
  unsigned short* G3u = (unsigned short*)sm;                  // [64][72]
  unsigned short* XBh = (unsigned short*)(sm + 4352);         // [32][72]
  unsigned short* H1u = (unsigned short*)(sm + 5504);         // [64][40]
  unsigned short* GBu = (unsigned short*)(sm + 6784);         // [64][72]
  unsigned short* T2u = (unsigned short*)(sm + 4352);         // [64][136]
  float*          RD  = sm + 8704;                            // [256]
  unsigned short* HBh = (unsigned short*)(sm + 8704);         // [32][72]

  const int t = threadIdx.x;
  const int n = blockIdx.x;
  if (n >= nTot) return;

  const int W    = t >> 6;
  const int lane = t & 63;
  const int quad = lane >> 4;
  const int l16  = lane & 15;
  const int hcol = W * 16 + l16;   // this wave's output column

  const float* gx = x + (size_t)n * 1600;
  const short8 z8 = (short8){0,0,0,0,0,0,0,0};

  // ---- constant A-fragments from to_grid_mat (sample-invariant) ----
  // phase 3b A: row s = W*16+l16, k = m = quad*8+j  (zero-pad m>=25)
  short8 tg3b;
  {
    const int s = W * 16 + l16;
    #pragma unroll
    for (int j = 0; j < 8; ++j) {
      int m = quad * 8 + j;
      tg3b[j] = (m < 25) ? bfs(tgm[s * 25 + m]) : (short)0;
    }
  }
  // phase 7 A: row m = mt*16+l16, k = s = ks*32+quad*8+j (zero rows m>=25)
  short8 a7[2][2];
  #pragma unroll
  for (int mt = 0; mt < 2; ++mt)
    #pragma unroll
    for (int ks = 0; ks < 2; ++ks) {
      int m = mt * 16 + l16;
      short8 a = z8;
      if (m < 25) {
        #pragma unroll
        for (int j = 0; j < 8; ++j) {
          int s = ks * 32 + quad * 8 + j;
          a[j] = bfs(tgm[s * 25 + m]);
        }
      }
      a7[mt][ks] = a;
    }

  // ---- phase 0: stage x -> XB f32 ----
  for (int f = 4 * t; f < 1600; f += 1024) {
    float4 v = *(const float4*)(gx + f);
    int m = f >> 6, c = f & 63;
    *(float4*)(XB + m * 68 + c) = v;
  }
  __syncthreads();

  // ---- phase 1: norms ----
  {
    float part = 0.f;
    for (int f = 64 + t; f < 1600; f += 256) {
      int m = f >> 6, c = f & 63;
      float v = XB[m * 68 + c];
      int l = deg_of(m);
      part += v * v * (1.f / (float)((2 * l + 1) * 4));
    }
    RD[t] = part;
  }
  __syncthreads();
  if (t < 64) {
    float s4 = RD[t] + RD[t + 64] + RD[t + 128] + RD[t + 192];
    #pragma unroll
    for (int o = 32; o >= 1; o >>= 1) s4 += __shfl_xor(s4, o, 64);
    if (t == 0) RD[0] = rsqrtf(s4 * (1.f / 64.f) + EPSV);
  } else if (t < 128) {
    int c = t - 64;
    float v = XB[c];
    float s1 = v, s2 = v * v;
    #pragma unroll
    for (int o = 32; o >= 1; o >>= 1) {
      s1 += __shfl_xor(s1, o, 64);
      s2 += __shfl_xor(s2, o, 64);
    }
    float mu  = s1 * (1.f / 64.f);
    float var = s2 * (1.f / 64.f) - mu * mu;
    XB[c] = (v - mu) * rsqrtf(var + EPSV) * nl0w[c] + nl0b[c];
  }
  __syncthreads();

  // ---- phase 1b: xn -> bf16 (XBh), zero H1u k-padding cols 25..31 ----
  {
    float inv = RD[0];
    for (int f = t; f < 1600; f += 256) {
      int m = f >> 6, c = f & 63;
      float v = XB[m * 68 + c];
      if (m > 0) v *= inv * affw[(deg_of(m) - 1) * 64 + c];
      XBh[m * 72 + c] = f2bf(v);
    }
    for (int i = t; i < 448; i += 256) {
      int r = i / 7, k = 25 + i % 7;
      H1u[r * 40 + k] = 0;
    }
  }
  __syncthreads();

  // ---- phase 3 (MFMA): h1 = xn @ lin1_w[deg]; gating = silu(xn0@scw+scb) ----
  float gval;
  {
    short8 a0[2], a1[2];
    #pragma unroll
    for (int ks = 0; ks < 2; ++ks) {
      a0[ks] = *(const short8*)(XBh + l16 * 72 + ks * 32 + quad * 8);
      a1[ks] = *(const short8*)(XBh + (16 + l16) * 72 + ks * 32 + quad * 8);
    }
    const int dl = deg_of(l16);
    short8 B[12];  // [l*2+ks] for l1w, [10+ks] for scw
    #pragma unroll
    for (int l = 0; l < 5; ++l)
      #pragma unroll
      for (int ks = 0; ks < 2; ++ks) {
        const float* wp = l1w + l * 4096 + (size_t)(ks * 32 + quad * 8) * 64 + hcol;
        short8 bb;
        #pragma unroll
        for (int j = 0; j < 8; ++j) bb[j] = bfs(wp[j * 64]);
        B[l * 2 + ks] = bb;
      }
    #pragma unroll
    for (int ks = 0; ks < 2; ++ks) {
      const float* wp = scw + (size_t)(ks * 32 + quad * 8) * 64 + hcol;
      short8 bb;
      #pragma unroll
      for (int j = 0; j < 8; ++j) bb[j] = bfs(wp[j * 64]);
      B[10 + ks] = bb;
    }
    f32x4 c0 = (f32x4){0,0,0,0}, c1 = (f32x4){0,0,0,0}, cg = (f32x4){0,0,0,0};
    #pragma unroll
    for (int ks = 0; ks < 2; ++ks) {
      #pragma unroll
      for (int l = 0; l < 4; ++l) {
        short8 am = (dl == l) ? a0[ks] : z8;
        c0 = __builtin_amdgcn_mfma_f32_16x16x32_bf16(am, B[l * 2 + ks], c0, 0, 0, 0);
      }
      c1 = __builtin_amdgcn_mfma_f32_16x16x32_bf16(a1[ks], B[8 + ks], c1, 0, 0, 0);
      short8 ag = (l16 == 0) ? a0[ks] : z8;
      cg = __builtin_amdgcn_mfma_f32_16x16x32_bf16(ag, B[10 + ks], cg, 0, 0, 0);
    }
    // D-writes: h1 transposed -> H1u[h][m], bias on m==0
    #pragma unroll
    for (int r = 0; r < 4; ++r) {
      int m = quad * 4 + r;
      float v = c0[r] + ((m == 0) ? l1b[hcol] : 0.f);
      H1u[hcol * 40 + m] = f2bf(v);
    }
    #pragma unroll
    for (int r = 0; r < 4; ++r) {
      int m = 16 + quad * 4 + r;
      if (m < 25) H1u[hcol * 40 + m] = f2bf(c1[r]);
    }
    gval = silu_f(cg[0] + scb[hcol]);  // valid on quad==0 lanes (row 0)
  }
  __syncthreads();

  // ---- phase 3b (MFMA): g = to_grid @ h1 ----
  {
    f32x4 cg3[4];
    #pragma unroll
    for (int nt = 0; nt < 4; ++nt) cg3[nt] = (f32x4){0,0,0,0};
    #pragma unroll
    for (int nt = 0; nt < 4; ++nt) {
      short8 b = *(const short8*)(H1u + (nt * 16 + l16) * 40 + quad * 8);
      cg3[nt] = __builtin_amdgcn_mfma_f32_16x16x32_bf16(tg3b, b, cg3[nt], 0, 0, 0);
    }
    #pragma unroll
    for (int nt = 0; nt < 4; ++nt)
      #pragma unroll
      for (int r = 0; r < 4; ++r) {
        int s = W * 16 + quad * 4 + r;
        GBu[s * 72 + nt * 16 + l16] = f2bf(cg3[nt][r]);
      }
  }
  __syncthreads();

  // ---- phase 4 (MFMA): t1 = silu(g @ w1), 64x64 @ 64x128 ----
  {
    short8 bf[4];
    #pragma unroll
    for (int nt2 = 0; nt2 < 2; ++nt2)
      #pragma unroll
      for (int ks = 0; ks < 2; ++ks) {
        const float* wp = gw1 + (size_t)(ks * 32 + quad * 8) * 128 + (2 * W + nt2) * 16 + l16;
        short8 bb;
        #pragma unroll
        for (int j = 0; j < 8; ++j) bb[j] = bfs(wp[j * 128]);
        bf[nt2 * 2 + ks] = bb;
      }
    f32x4 acc[8];
    #pragma unroll
    for (int i = 0; i < 8; ++i) acc[i] = (f32x4){0,0,0,0};
    #pragma unroll
    for (int mt = 0; mt < 4; ++mt)
      #pragma unroll
      for (int ks = 0; ks < 2; ++ks) {
        short8 a = *(const short8*)(GBu + (mt * 16 + l16) * 72 + ks * 32 + quad * 8);
        acc[mt * 2 + 0] = __builtin_amdgcn_mfma_f32_16x16x32_bf16(a, bf[ks],     acc[mt * 2 + 0], 0, 0, 0);
        acc[mt * 2 + 1] = __builtin_amdgcn_mfma_f32_16x16x32_bf16(a, bf[2 + ks], acc[mt * 2 + 1], 0, 0, 0);
      }
    #pragma unroll
    for (int mt = 0; mt < 4; ++mt)
      #pragma unroll
      for (int nt2 = 0; nt2 < 2; ++nt2) {
        int col = (2 * W + nt2) * 16 + l16;
        #pragma unroll
        for (int r = 0; r < 4; ++r) {
          int srow = mt * 16 + quad * 4 + r;
          T1u[srow * 136 + col] = f2bf(silu_f(acc[mt * 2 + nt2][r]));
        }
      }
  }
  __syncthreads();

  // ---- phase 5 (MFMA): t2 = silu(t1 @ w2), 64x128 @ 128x128 ----
  {
    short8 bf[8];
    #pragma unroll
    for (int nt2 = 0; nt2 < 2; ++nt2)
      #pragma unroll
      for (int ks = 0; ks < 4; ++ks) {
        const float* wp = gw2 + (size_t)(ks * 32 + quad * 8) * 128 + (2 * W + nt2) * 16 + l16;
        short8 bb;
        #pragma unroll
        for (int j = 0; j < 8; ++j) bb[j] = bfs(wp[j * 128]);
        bf[nt2 * 4 + ks] = bb;
      }
    f32x4 acc[8];
    #pragma unroll
    for (int i = 0; i < 8; ++i) acc[i] = (f32x4){0,0,0,0};
    #pragma unroll
    for (int mt = 0; mt < 4; ++mt)
      #pragma unroll
      for (int ks = 0; ks < 4; ++ks) {
        short8 a = *(const short8*)(T1u + (mt * 16 + l16) * 136 + ks * 32 + quad * 8);
        acc[mt * 2 + 0] = __builtin_amdgcn_mfma_f32_16x16x32_bf16(a, bf[ks],     acc[mt * 2 + 0], 0, 0, 0);
        acc[mt * 2 + 1] = __builtin_amdgcn_mfma_f32_16x16x32_bf16(a, bf[4 + ks], acc[mt * 2 + 1], 0, 0, 0);
      }
    #pragma unroll
    for (int mt = 0; mt < 4; ++mt)
      #pragma unroll
      for (int nt2 = 0; nt2 < 2; ++nt2) {
        int col = (2 * W + nt2) * 16 + l16;
        #pragma unroll
        for (int r = 0; r < 4; ++r) {
          int srow = mt * 16 + quad * 4 + r;
          T2u[srow * 136 + col] = f2bf(silu_f(acc[mt * 2 + nt2][r]));
        }
      }
  }
  __syncthreads();

  // ---- phase 6 (MFMA): g3 = t2 @ w3, store transposed bf16 G3u[h][s] ----
  {
    short8 bf[4];
    #pragma unroll
    for (int ks = 0; ks < 4; ++ks) {
      const float* wp = gw3 + (size_t)(ks * 32 + quad * 8) * 64 + hcol;
      short8 bb;
      #pragma unroll
      for (int j = 0; j < 8; ++j) bb[j] = bfs(wp[j * 64]);
      bf[ks] = bb;
    }
    f32x4 acc[4];
    #pragma unroll
    for (int i = 0; i < 4; ++i) acc[i] = (f32x4){0,0,0,0};
    #pragma unroll
    for (int mt = 0; mt < 4; ++mt)
      #pragma unroll
      for (int ks = 0; ks < 4; ++ks) {
        short8 a = *(const short8*)(T2u + (mt * 16 + l16) * 136 + ks * 32 + quad * 8);
        acc[mt] = __builtin_amdgcn_mfma_f32_16x16x32_bf16(a, bf[ks], acc[mt], 0, 0, 0);
      }
    #pragma unroll
    for (int mt = 0; mt < 4; ++mt)
      #pragma unroll
      for (int r = 0; r < 4; ++r) {
        int s = mt * 16 + quad * 4 + r;
        G3u[hcol * 72 + s] = f2bf(acc[mt][r]);
      }
  }
  __syncthreads();

  // ---- phase 7 (MFMA): hb = to_grid^T @ g3 (rows 1..24); row 0 = gating ----
  {
    short8 b7[2];
    #pragma unroll
    for (int ks = 0; ks < 2; ++ks)
      b7[ks] = *(const short8*)(G3u + hcol * 72 + ks * 32 + quad * 8);
    f32x4 c7[2];
    #pragma unroll
    for (int mt = 0; mt < 2; ++mt) c7[mt] = (f32x4){0,0,0,0};
    #pragma unroll
    for (int mt = 0; mt < 2; ++mt)
      #pragma unroll
      for (int ks = 0; ks < 2; ++ks)
        c7[mt] = __builtin_amdgcn_mfma_f32_16x16x32_bf16(a7[mt][ks], b7[ks], c7[mt], 0, 0, 0);
    #pragma unroll
    for (int mt = 0; mt < 2; ++mt)
      #pragma unroll
      for (int r = 0; r < 4; ++r) {
        int m = mt * 16 + quad * 4 + r;
        if (m >= 1 && m < 25) HBh[m * 72 + hcol] = f2bf(c7[mt][r]);
      }
    if (quad == 0) HBh[hcol] = f2bf(gval);
  }
  __syncthreads();

  // ---- phase 8 (MFMA): out = hb @ lin2_w[deg] (+ lin2_b on row 0) ----
  {
    short8 a0[2], a1[2];
    #pragma unroll
    for (int ks = 0; ks < 2; ++ks) {
      a0[ks] = *(const short8*)(HBh + l16 * 72 + ks * 32 + quad * 8);
      a1[ks] = *(const short8*)(HBh + (16 + l16) * 72 + ks * 32 + quad * 8);
    }
    const int dl = deg_of(l16);
    short8 B[10];
    #pragma unroll
    for (int l = 0; l < 5; ++l)
      #pragma unroll
      for (int ks = 0; ks < 2; ++ks) {
        const float* wp = l2w + l * 4096 + (size_t)(ks * 32 + quad * 8) * 64 + hcol;
        short8 bb;
        #pragma unroll
        for (int j = 0; j < 8; ++j) bb[j] = bfs(wp[j * 64]);
        B[l * 2 + ks] = bb;
      }
    f32x4 c0 = (f32x4){0,0,0,0}, c1 = (f32x4){0,0,0,0};
    #pragma unroll
    for (int ks = 0; ks < 2; ++ks) {
      #pragma unroll
      for (int l = 0; l < 4; ++l) {
        short8 am = (dl == l) ? a0[ks] : z8;
        c0 = __builtin_amdgcn_mfma_f32_16x16x32_bf16(am, B[l * 2 + ks], c0, 0, 0, 0);
      }
      c1 = __builtin_amdgcn_mfma_f32_16x16x32_bf16(a1[ks], B[8 + ks], c1, 0, 0, 0);
    }
    float* go = out + (size_t)n * 1600;
    float bias = l2b[hcol];
    #pragma unroll
    for (int r = 0; r < 4; ++r) {
      int m = quad * 4 + r;
      go[m * 64 + hcol] = c0[r] + ((m == 0) ? bias : 0.f);
    }
    #pragma unroll
    for (int r = 0; r < 4; ++r) {
      int m = 16 + quad * 4 + r;
      if (m < 25) go[m * 64 + hcol] = c1[r];
    }
  }
}

extern "C" void kernel_launch(void* const* d_in, const int* in_sizes, int n_in,
                              void* d_out, int out_size, void* d_ws, size_t ws_size,
                              hipStream_t stream) {
  const float* x    = (const float*)d_in[0];
  const float* nl0w = (const float*)d_in[1];
  const float* nl0b = (const float*)d_in[2];
  const float* affw = (const float*)d_in[3];
  const float* l1w  = (const float*)d_in[4];
  const float* l1b  = (const float*)d_in[5];
  const float* scw  = (const float*)d_in[6];
  const float* scb  = (const float*)d_in[7];
  const float* gw1  = (const float*)d_in[8];
  const float* gw2  = (const float*)d_in[9];
  const float* gw3  = (const float*)d_in[10];
  const float* l2w  = (const float*)d_in[11];
  const float* l2b  = (const float*)d_in[12];
  const float* tgm  = (const float*)d_in[13];

  int N = in_sizes[0] / 1600;
  fused_sample_kernel<<<dim3(N), dim3(256), 0, stream>>>(
      x, nl0w, nl0b, affw, l1w, l1b, scw, scb,
      gw1, gw2, gw3, l2w, l2b, tgm, (float*)d_out, N);
}